// Round 13
// baseline (966.525 us; speedup 1.0000x reference)
//
#include <hip/hip_runtime.h>

typedef short short8 __attribute__((ext_vector_type(8)));
typedef float f32x4 __attribute__((ext_vector_type(4)));

#define DEVI __device__ __forceinline__

constexpr int BATCH = 8;
constexpr int NPTS  = 65536;     // points per batch
constexpr int CIN   = 6;
constexpr int H0    = 128;
constexpr int H1    = 256;
constexpr int NCTR  = 1024;
constexpr int MB    = 64;        // points per block
constexpr int NCHUNK = 8;        // sort chunks per batch
constexpr int CHSZ  = NPTS / NCHUNK;   // 8192
constexpr int NTILE = 4;         // tiles per persistent phase2 block
constexpr int P2GRID = BATCH * NPTS / MB / NTILE;   // 2048

// a-tile strides (shorts), padded for bank-conflict-free ds_read_b128
constexpr int A1S = 136;         // 128 + 8
constexpr int A2S = 264;         // 256 + 8

constexpr int CAP1 = 8;          // LDS-reduced slots, phase1 (8*128*4 = 4 KB)
constexpr int CAP2 = 4;          // phase2 (4*256*4 = 4 KB, union'd with stats)

// workspace layout
constexpr size_t Y_BYTES  = (size_t)BATCH * NCTR * H0 * 4;      // 4 MiB fp32
constexpr size_t W2T_OFF  = Y_BYTES;
constexpr size_t W3T_OFF  = W2T_OFF + (size_t)H0 * H0 * 2;
constexpr size_t W4T_OFF  = W3T_OFF + (size_t)H1 * H1 * 2;
constexpr size_t SORT_OFF = W4T_OFF + (size_t)H1 * H1 * 2;
constexpr size_t CH_OFF   = SORT_OFF + (size_t)BATCH * NPTS * 4;
constexpr size_t CB_OFF   = CH_OFF + (size_t)BATCH * NCHUNK * NCTR * 4;
constexpr size_t NZR_OFF  = CB_OFF + (size_t)BATCH * NCHUNK * NCTR * 4;
constexpr size_t YQ_OFF   = NZR_OFF + (size_t)BATCH * NCTR * 4;
constexpr size_t WS_NEED  = YQ_OFF + (size_t)BATCH * NCTR * H0 * 2;       // ~9 MB
constexpr size_t XQ_OFF   = WS_NEED;
constexpr size_t WS_XQ    = XQ_OFF + (size_t)BATCH * NPTS * H0 * 2;       // +128 MB

DEVI unsigned short f2bf(float f) {
    unsigned u = __float_as_uint(f);
    u += 0x7fffu + ((u >> 16) & 1u);          // round-to-nearest-even
    return (unsigned short)(u >> 16);
}
// tanh-form GELU, branch-free (~8 VALU vs ~70 for erff). |err| <~1e-3, fine at bf16 scale.
DEVI float gelu(float x) {
    const float x3 = x * x * x;
    const float u = fmaf(x3, -0.07135481283f, -1.5957691216f * x);
    return x * __builtin_amdgcn_rcpf(1.f + __expf(u));
}

// ---------------- conv1: gelu(LN(p@w1+b1)) -> a1[64][A1S] bf16 ----------------
DEVI void conv1_tile(int tid, const float* s_pts, const float* s_w1,
                     const float* s_b1, const float* s_g1, const float* s_be1,
                     unsigned short* a1)
{
    const int p = tid >> 2, sub = tid & 3;    // 4 threads per point, c = 4j+sub
    float pt[CIN];
#pragma unroll
    for (int k = 0; k < CIN; ++k) pt[k] = s_pts[p * CIN + k];
    float h[32];
#pragma unroll
    for (int j = 0; j < 32; ++j) {
        const int c = (j << 2) + sub;
        float a = s_b1[c];
#pragma unroll
        for (int k = 0; k < CIN; ++k) a = fmaf(pt[k], s_w1[k * H0 + c], a);
        h[j] = a;
    }
    float s = 0.f, s2 = 0.f;
#pragma unroll
    for (int j = 0; j < 32; ++j) { s += h[j]; s2 = fmaf(h[j], h[j], s2); }
    s  += __shfl_xor(s, 1);  s  += __shfl_xor(s, 2);
    s2 += __shfl_xor(s2, 1); s2 += __shfl_xor(s2, 2);
    const float mean = s * (1.f / H0);
    const float rstd = rsqrtf(s2 * (1.f / H0) - mean * mean + 1e-5f);
#pragma unroll
    for (int j = 0; j < 32; ++j) {
        const int c = (j << 2) + sub;
        float v = fmaf((h[j] - mean) * rstd, s_g1[c], s_be1[c]);
        a1[p * A1S + c] = f2bf(gelu(v));
    }
}

// ---------------- GEMM2 (shared helper) ----------------
DEVI void gemm2(int lane, int wave, const unsigned short* a1,
                const unsigned short* __restrict__ w2T, f32x4 (&acc)[4][2])
{
    const int q = lane >> 4, colw = lane & 15, n0 = wave * 32;
#pragma unroll
    for (int ks = 0; ks < 4; ++ks) {
        short8 af[4], bfr[2];
#pragma unroll
        for (int mt = 0; mt < 4; ++mt)
            af[mt] = *(const short8*)&a1[(mt * 16 + colw) * A1S + ks * 32 + q * 8];
#pragma unroll
        for (int nt = 0; nt < 2; ++nt)
            bfr[nt] = *(const short8*)&w2T[(n0 + nt * 16 + colw) * H0 + ks * 32 + q * 8];
#pragma unroll
        for (int mt = 0; mt < 4; ++mt)
#pragma unroll
            for (int nt = 0; nt < 2; ++nt)
                acc[mt][nt] = __builtin_amdgcn_mfma_f32_16x16x32_bf16(
                    af[mt], bfr[nt], acc[mt][nt], 0, 0, 0);
    }
}

// stage sorted point metadata (tid<64). Clamped: no OOB even on garbage input.
DEVI void stage_sorted(int tid, int b, int P0, const int* __restrict__ sorted,
                       const float* __restrict__ pts, float* s_pts, int* s_idx)
{
    if (tid < 64) {
        const int val = sorted[P0 + tid];
        const int pid = val & 0xFFFF;
        s_idx[tid] = (val >> 16) & (NCTR - 1);
        const float* prow = &pts[((size_t)(b << 16) + pid) * CIN];
#pragma unroll
        for (int k = 0; k < CIN; ++k) s_pts[tid * CIN + k] = prow[k];
    }
}

// parallel slot assignment (fallback path only): Hillis-Steele scan.
DEVI void slot_scan(int tid, const int* s_idx, int* s_slot, int* s_slotc, int* s_nslot, int cap)
{
    int f = 0;
    if (tid < MB) {
        f = (tid > 0 && s_idx[tid] != s_idx[tid - 1]) ? 1 : 0;
        s_slot[tid] = f;
    }
    __syncthreads();
#pragma unroll
    for (int off = 1; off < MB; off <<= 1) {
        int t = 0;
        if (tid < MB && tid >= off) t = s_slot[tid - off];
        __syncthreads();
        if (tid < MB) s_slot[tid] += t;
        __syncthreads();
    }
    if (tid < MB) {
        const int s = s_slot[tid];
        if ((f || tid == 0) && s < cap) s_slotc[s] = s_idx[tid];
        if (tid == MB - 1) *s_nslot = (s + 1 < cap) ? (s + 1) : cap;
    }
    __syncthreads();
}

// ---------------- prep: weight convert/transpose ----------------
__global__ __launch_bounds__(256) void k_prep(
    const float* __restrict__ w2, const float* __restrict__ w3,
    const float* __restrict__ w4,
    unsigned short* __restrict__ w2T, unsigned short* __restrict__ w3T,
    unsigned short* __restrict__ w4T)
{
    int t = blockIdx.x * 256 + threadIdx.x;
    if (t < H0 * H0) {
        int n = t >> 7, k = t & 127;
        w2T[t] = f2bf(w2[k * H0 + n]);
    }
    int t3 = t - H0 * H0;
    if (t3 >= 0 && t3 < H1 * H1) {
        int n = t3 >> 8, k = t3 & 255;
        w3T[t3] = f2bf(w3[k * H1 + n]);
    }
    int t4 = t - (H0 * H0 + H1 * H1);
    if (t4 >= 0 && t4 < H1 * H1) {
        int n = t4 >> 8, k = t4 & 255;
        w4T[t4] = f2bf(w4[k * H1 + n]);
    }
}

// ---------------- y (fp32) -> yq (bf16) ----------------
__global__ __launch_bounds__(256) void k_yq(const float* __restrict__ y,
                                            unsigned short* __restrict__ yq)
{
    const int i = blockIdx.x * 256 + threadIdx.x;   // 1 elem4 per thread
    const float4 v = *(const float4*)&y[(size_t)i * 4];
    uint2 pk;
    pk.x = (unsigned)f2bf(v.x) | ((unsigned)f2bf(v.y) << 16);
    pk.y = (unsigned)f2bf(v.z) | ((unsigned)f2bf(v.w) << 16);
    *(uint2*)&yq[(size_t)i * 4] = pk;
}

// ---------------- sort: chunked hist -> deterministic 2-level scan -> scatter ----
__global__ __launch_bounds__(256) void k_hist(const int* __restrict__ nn,
                                              int* __restrict__ ch)
{
    __shared__ int lh[NCTR];
    const int tid = threadIdx.x;
    const int b = blockIdx.x >> 3, k = blockIdx.x & 7;
    const int base = (b << 16) + k * CHSZ;
    for (int c = tid; c < NCTR; c += 256) lh[c] = 0;
    __syncthreads();
    for (int i = tid; i < CHSZ; i += 256)
        atomicAdd(&lh[nn[base + i] & (NCTR - 1)], 1);
    __syncthreads();
    for (int c = tid; c < NCTR; c += 256) ch[(blockIdx.x << 10) + c] = lh[c];
}

// scan: per-chunk cursor bases + nzrank (# nonempty centers < c) per batch
__global__ __launch_bounds__(256) void k_scan(const int* __restrict__ ch,
                                              int* __restrict__ cb,
                                              int* __restrict__ nzr)
{
    __shared__ int part[256], partz[256];
    const int tid = threadIdx.x;
    const int b = tid >> 5, t = tid & 31;     // 32 threads per batch, 32 centers each
    const int c0 = t * 32;
    int tot = 0, totz = 0;
    for (int c = c0; c < c0 + 32; ++c) {
        int cnt = 0;
        for (int k = 0; k < NCHUNK; ++k)
            cnt += ch[((b * NCHUNK + k) << 10) + c];
        tot += cnt; totz += (cnt > 0);
    }
    part[tid] = tot; partz[tid] = totz;
    __syncthreads();
    if (t == 0) {                              // serial scan of 32 partials per batch
        int run = 0, runz = 0;
        for (int i = 0; i < 32; ++i) {
            const int v  = part[(b << 5) + i];  part[(b << 5) + i]  = run;  run  += v;
            const int vz = partz[(b << 5) + i]; partz[(b << 5) + i] = runz; runz += vz;
        }
    }
    __syncthreads();
    int run = part[tid], runz = partz[tid];
    for (int c = c0; c < c0 + 32; ++c) {
        int cnt = 0;
        for (int k = 0; k < NCHUNK; ++k) {
            const int idx = ((b * NCHUNK + k) << 10) + c;
            cb[idx] = run; run += ch[idx]; cnt += ch[idx];
        }
        nzr[(b << 10) + c] = runz;
        runz += (cnt > 0);
    }
}

__global__ __launch_bounds__(256) void k_scatter(const int* __restrict__ nn,
                                                 const int* __restrict__ cb,
                                                 int* __restrict__ sorted)
{
    __shared__ int cur[NCTR];
    const int tid = threadIdx.x;
    const int b = blockIdx.x >> 3, k = blockIdx.x & 7;
    const int base = (b << 16) + k * CHSZ;
    for (int c = tid; c < NCTR; c += 256) cur[c] = cb[(blockIdx.x << 10) + c];
    __syncthreads();
    for (int i = tid; i < CHSZ; i += 256) {
        const int c = nn[base + i] & (NCTR - 1);
        const int pos = atomicAdd(&cur[c], 1);
        if ((unsigned)pos < (unsigned)NPTS)             // paranoia: cannot fault
            sorted[(b << 16) + pos] = (k * CHSZ + i) | (c << 16);
    }
}

// ---------------- phase 1: conv1 MLP + slot-reduced max into y (+ optional x store) ----
template <bool XQ>
__global__ __launch_bounds__(256, 4) void k_phase1(
    const int* __restrict__ sorted, const float* __restrict__ pts,
    const int* __restrict__ nzr,
    const float* __restrict__ w1, const float* __restrict__ b1,
    const float* __restrict__ g1, const float* __restrict__ be1,
    const unsigned short* __restrict__ w2T, const float* __restrict__ b2,
    float* __restrict__ y, unsigned short* __restrict__ xq)
{
    __shared__ __align__(16) float s_pts[MB * CIN];
    __shared__ int   s_idx[MB], s_slot[MB], s_slotc[CAP1], s_nslot;
    __shared__ float s_w1[CIN * H0];
    __shared__ float s_b1[H0], s_g1[H0], s_be1[H0];
    __shared__ __align__(16) unsigned short a1[MB * A1S];
    __shared__ int   red1[CAP1 * H0];

    const int tid = threadIdx.x;
    const int P0  = blockIdx.x * MB;
    const int b   = P0 >> 16;
    const int lane = tid & 63, wave = tid >> 6;
    const int q = lane >> 4, colw = lane & 15, n0 = wave * 32;

    if (tid < 64) {
        const int val = sorted[P0 + tid];
        const int pid = val & 0xFFFF;
        const int c   = (val >> 16) & (NCTR - 1);
        const int c0v = (sorted[P0] >> 16) & (NCTR - 1);
        s_idx[tid] = c;
        const int sl = nzr[(b << 10) + c] - nzr[(b << 10) + c0v];  // run rank in tile
        s_slot[tid] = sl;
        if (tid == 63) s_nslot = (sl + 1 < CAP1) ? (sl + 1) : CAP1;
        const float* prow = &pts[((size_t)(b << 16) + pid) * CIN];
#pragma unroll
        for (int k = 0; k < CIN; ++k) s_pts[tid * CIN + k] = prow[k];
    }
    for (int i = tid; i < CIN * H0; i += 256) s_w1[i] = w1[i];
    if (tid < H0) { s_b1[tid] = b1[tid]; s_g1[tid] = g1[tid]; s_be1[tid] = be1[tid]; }
    for (int i = tid; i < CAP1 * H0; i += 256) red1[i] = 0;
    __syncthreads();                                    // [A]

    if (tid < 64) {
        const int sl = s_slot[tid];
        if (sl < CAP1 && (tid == 0 || s_idx[tid] != s_idx[tid - 1]))
            s_slotc[sl] = s_idx[tid];
    }
    conv1_tile(tid, s_pts, s_w1, s_b1, s_g1, s_be1, a1);
    __syncthreads();                                    // [B] a1 + slotc ready

    f32x4 acc[4][2] = {};
    gemm2(lane, wave, a1, w2T, acc);
    if (XQ) __syncthreads();              // [C] a1 MFMA reads done before x restage

    // per-thread bias cols (2) straight from global (L2-hot), loaded at use
    float b2reg[2];
#pragma unroll
    for (int nt = 0; nt < 2; ++nt) b2reg[nt] = b2[n0 + nt * 16 + colw];

    int* yi = (int*)y;
    // ---- slot-grouped in-register max, then few atomics ----
    {
        float vm[2] = {-3.4e38f, -3.4e38f};
        int cur = s_slot[q * 4], curc = s_idx[q * 4];
#pragma unroll
        for (int mt = 0; mt < 4; ++mt)
#pragma unroll
            for (int r = 0; r < 4; ++r) {
                const int row = mt * 16 + q * 4 + r;
                const int s = s_slot[row];
                if (s != cur) {
#pragma unroll
                    for (int nt = 0; nt < 2; ++nt) {
                        if (vm[nt] > 0.f) {
                            const int col = n0 + nt * 16 + colw;
                            if (cur < CAP1) atomicMax(&red1[cur * H0 + col], __float_as_int(vm[nt]));
                            else atomicMax(&yi[(((b << 10) + curc) << 7) + col], __float_as_int(vm[nt]));
                        }
                        vm[nt] = -3.4e38f;
                    }
                    cur = s; curc = s_idx[row];
                }
#pragma unroll
                for (int nt = 0; nt < 2; ++nt) {
                    const float v = acc[mt][nt][r] + b2reg[nt];
                    if (XQ) a1[row * A1S + n0 + nt * 16 + colw] = f2bf(v);
                    vm[nt] = fmaxf(vm[nt], v);
                }
            }
#pragma unroll
        for (int nt = 0; nt < 2; ++nt)
            if (vm[nt] > 0.f) {
                const int col = n0 + nt * 16 + colw;
                if (cur < CAP1) atomicMax(&red1[cur * H0 + col], __float_as_int(vm[nt]));
                else atomicMax(&yi[(((b << 10) + curc) << 7) + col], __float_as_int(vm[nt]));
            }
    }
    __syncthreads();                                    // [D]
    const int nsc = s_nslot;
    for (int i = tid; i < nsc * H0; i += 256) {
        const int v = red1[i];
        if (v > 0)
            atomicMax(&yi[(((b << 10) + s_slotc[i >> 7]) << 7) + (i & 127)], v);
    }
    if (XQ) {   // coalesced x store: 1024 short8 units
        for (int i = tid; i < MB * (H0 / 8); i += 256) {
            const int row = i >> 4, u = (i & 15) * 8;
            *(short8*)&xq[((size_t)P0 + row) * H0 + u] = *(const short8*)&a1[row * A1S + u];
        }
    }
}

// ---------------- phase 2 (XQ): persistent, 4 tiles/block, cross-tile pipeline ----
// Staging for tile t+1 issued into regs right after [A] of tile t; written to
// LDS at the top of the next iteration (T14 across tiles).
__global__ __launch_bounds__(512, 6) void k_phase2x(
    const int* __restrict__ sorted, const unsigned short* __restrict__ xq,
    const unsigned short* __restrict__ yq, const int* __restrict__ nzr,
    const unsigned short* __restrict__ w3T, const float* __restrict__ b3,
    const float* __restrict__ g2, const float* __restrict__ be2,
    const unsigned short* __restrict__ w4T, const float* __restrict__ b4,
    float* __restrict__ outp)
{
    __shared__ int   s_idx[MB], s_slot[MB], s_slotc[CAP2], s_nslot;
    __shared__ __align__(16) unsigned short a2[MB * A2S];
    __shared__ union __align__(16) {
        float2 stats[MB * 8];            // 4096 B (dead after rowstat)
        int    red[CAP2 * H1];           // 4096 B (epilogue on)
    } u2;
    __shared__ float2 s_rowstat[MB];

    const int tid = threadIdx.x;
    const int lane = tid & 63, wave = tid >> 6;   // wave 0..7
    const int q = lane >> 4, colw = lane & 15;
    const int n0 = wave * 32;                      // 32-col strip per wave
    const int rowp = tid >> 3, sub = tid & 7;
    int* outi = (int*)outp;

    // ---- prologue: load tile 0 staging into regs ----
    int P0 = blockIdx.x * MB;
    short8 sv0, sv1, sv2, sv3;
    {
        const int sval = sorted[P0 + rowp];
        const int cp = (sval >> 16) & (NCTR - 1);
        const int b0 = P0 >> 16;
        const unsigned short* src = (sub < 4)
            ? &yq[((size_t)((b0 << 10) + cp)) * H0 + sub * 32]
            : &xq[((size_t)P0 + rowp) * H0 + (sub - 4) * 32];
        sv0 = *(const short8*)(src);
        sv1 = *(const short8*)(src + 8);
        sv2 = *(const short8*)(src + 16);
        sv3 = *(const short8*)(src + 24);
    }

    for (int t = 0; t < NTILE; ++t) {
        const int b = P0 >> 16;
        {   // write staged regs -> a2
            unsigned short* dst = (sub < 4)
                ? &a2[rowp * A2S + sub * 32]
                : &a2[rowp * A2S + H0 + (sub - 4) * 32];
            *(short8*)(dst)      = sv0;
            *(short8*)(dst + 8)  = sv1;
            *(short8*)(dst + 16) = sv2;
            *(short8*)(dst + 24) = sv3;
        }
        if (tid < 64) {
            const int c   = (sorted[P0 + tid] >> 16) & (NCTR - 1);
            const int c0v = (sorted[P0] >> 16) & (NCTR - 1);
            s_idx[tid] = c;
            const int sl = nzr[(b << 10) + c] - nzr[(b << 10) + c0v];
            s_slot[tid] = sl;
            if (tid == 63) s_nslot = (sl + 1 < CAP2) ? (sl + 1) : CAP2;
        }
        __syncthreads();                                // [A] a2 + slots ready

        // ---- issue next-tile staging loads (hide under this tile's compute) ----
        const int P0n = P0 + P2GRID * MB;
        if (t + 1 < NTILE) {
            const int svaln = sorted[P0n + rowp];
            const int cpn = (svaln >> 16) & (NCTR - 1);
            const int bn = P0n >> 16;
            const unsigned short* srcn = (sub < 4)
                ? &yq[((size_t)((bn << 10) + cpn)) * H0 + sub * 32]
                : &xq[((size_t)P0n + rowp) * H0 + (sub - 4) * 32];
            sv0 = *(const short8*)(srcn);
            sv1 = *(const short8*)(srcn + 8);
            sv2 = *(const short8*)(srcn + 16);
            sv3 = *(const short8*)(srcn + 24);
        }
        if (tid < 64) {
            const int sl = s_slot[tid];
            if (sl < CAP2 && (tid == 0 || s_idx[tid] != s_idx[tid - 1]))
                s_slotc[sl] = s_idx[tid];
        }

        // ---- GEMM3: a2[64][256] @ w3T -> 64x32 strip ----
        f32x4 acc3[4][2] = {};
#pragma unroll
        for (int ks = 0; ks < 8; ++ks) {
            short8 af[4], bfr[2];
#pragma unroll
            for (int mt = 0; mt < 4; ++mt)
                af[mt] = *(const short8*)&a2[(mt * 16 + colw) * A2S + ks * 32 + q * 8];
#pragma unroll
            for (int nt = 0; nt < 2; ++nt)
                bfr[nt] = *(const short8*)&w3T[(n0 + nt * 16 + colw) * H1 + ks * 32 + q * 8];
#pragma unroll
            for (int mt = 0; mt < 4; ++mt)
#pragma unroll
                for (int nt = 0; nt < 2; ++nt)
                    acc3[mt][nt] = __builtin_amdgcn_mfma_f32_16x16x32_bf16(
                        af[mt], bfr[nt], acc3[mt][nt], 0, 0, 0);
        }

        // + b3 (loaded at use), then LN partial sums (this wave's 32 cols)
        {
            float b3r[2];
#pragma unroll
            for (int nt = 0; nt < 2; ++nt) b3r[nt] = b3[n0 + nt * 16 + colw];
#pragma unroll
            for (int mt = 0; mt < 4; ++mt)
#pragma unroll
                for (int nt = 0; nt < 2; ++nt)
#pragma unroll
                    for (int r = 0; r < 4; ++r)
                        acc3[mt][nt][r] += b3r[nt];
        }

#pragma unroll
        for (int mt = 0; mt < 4; ++mt)
#pragma unroll
            for (int r = 0; r < 4; ++r) {
                float s = 0.f, s2 = 0.f;
#pragma unroll
                for (int nt = 0; nt < 2; ++nt) {
                    float v = acc3[mt][nt][r];
                    s += v; s2 = fmaf(v, v, s2);
                }
                s  += __shfl_xor(s, 1);  s  += __shfl_xor(s, 2);
                s  += __shfl_xor(s, 4);  s  += __shfl_xor(s, 8);
                s2 += __shfl_xor(s2, 1); s2 += __shfl_xor(s2, 2);
                s2 += __shfl_xor(s2, 4); s2 += __shfl_xor(s2, 8);
                if (colw == 0)
                    u2.stats[(mt * 16 + q * 4 + r) * 8 + wave] = make_float2(s, s2);
            }
        __syncthreads();                                // [B]
        if (tid < MB) {
            float S = 0.f, S2 = 0.f;
#pragma unroll
            for (int w = 0; w < 8; ++w) { float2 tt = u2.stats[tid * 8 + w]; S += tt.x; S2 += tt.y; }
            const float mean = S * (1.f / H1);
            const float rstd = rsqrtf(S2 * (1.f / H1) - mean * mean + 1e-5f);
            s_rowstat[tid] = make_float2(mean, rstd);
        }
        __syncthreads();                                // [C] stats dead from here

        // normalize + gelu -> h back into a2 (this wave's 32 cols); also zero red
        {
            float g2r[2], be2r[2];
#pragma unroll
            for (int nt = 0; nt < 2; ++nt) {
                const int col = n0 + nt * 16 + colw;
                g2r[nt] = g2[col]; be2r[nt] = be2[col];
            }
#pragma unroll
            for (int mt = 0; mt < 4; ++mt)
#pragma unroll
                for (int r = 0; r < 4; ++r) {
                    const int row = mt * 16 + q * 4 + r;
                    const float2 ms = s_rowstat[row];
#pragma unroll
                    for (int nt = 0; nt < 2; ++nt) {
                        float v = (acc3[mt][nt][r] - ms.x) * ms.y;
                        v = fmaf(v, g2r[nt], be2r[nt]);
                        a2[row * A2S + n0 + nt * 16 + colw] = f2bf(gelu(v));
                    }
                }
        }
        for (int i = tid; i < CAP2 * H1; i += 512) u2.red[i] = 0;
        __syncthreads();                                // [D] h written + red zeroed

        // ---- GEMM4: h[64][256] @ w4T -> 64x32 strip ----
        f32x4 acc4[4][2] = {};
#pragma unroll
        for (int ks = 0; ks < 8; ++ks) {
            short8 af[4], bfr[2];
#pragma unroll
            for (int mt = 0; mt < 4; ++mt)
                af[mt] = *(const short8*)&a2[(mt * 16 + colw) * A2S + ks * 32 + q * 8];
#pragma unroll
            for (int nt = 0; nt < 2; ++nt)
                bfr[nt] = *(const short8*)&w4T[(n0 + nt * 16 + colw) * H1 + ks * 32 + q * 8];
#pragma unroll
            for (int mt = 0; mt < 4; ++mt)
#pragma unroll
                for (int nt = 0; nt < 2; ++nt)
                    acc4[mt][nt] = __builtin_amdgcn_mfma_f32_16x16x32_bf16(
                        af[mt], bfr[nt], acc4[mt][nt], 0, 0, 0);
        }
        // no barrier: epilogue atomics target u2.red (disjoint from a2)

        float b4r[2];
#pragma unroll
        for (int nt = 0; nt < 2; ++nt) b4r[nt] = b4[n0 + nt * 16 + colw];

        // ---- slot-grouped in-register max, then few atomics ----
        {
            float vm[2] = {-3.4e38f, -3.4e38f};
            int cur = s_slot[q * 4], curc = s_idx[q * 4];
#pragma unroll
            for (int mt = 0; mt < 4; ++mt)
#pragma unroll
                for (int r = 0; r < 4; ++r) {
                    const int row = mt * 16 + q * 4 + r;
                    const int s = s_slot[row];
                    if (s != cur) {
#pragma unroll
                        for (int nt = 0; nt < 2; ++nt) {
                            if (vm[nt] > 0.f) {
                                const int col = n0 + nt * 16 + colw;
                                if (cur < CAP2) atomicMax(&u2.red[cur * H1 + col], __float_as_int(vm[nt]));
                                else atomicMax(&outi[(((size_t)(b << 10) + curc) << 8) + col], __float_as_int(vm[nt]));
                            }
                            vm[nt] = -3.4e38f;
                        }
                        cur = s; curc = s_idx[row];
                    }
#pragma unroll
                    for (int nt = 0; nt < 2; ++nt)
                        vm[nt] = fmaxf(vm[nt], acc4[mt][nt][r] + b4r[nt]);
                }
#pragma unroll
            for (int nt = 0; nt < 2; ++nt)
                if (vm[nt] > 0.f) {
                    const int col = n0 + nt * 16 + colw;
                    if (cur < CAP2) atomicMax(&u2.red[cur * H1 + col], __float_as_int(vm[nt]));
                    else atomicMax(&outi[(((size_t)(b << 10) + curc) << 8) + col], __float_as_int(vm[nt]));
                }
        }
        __syncthreads();                                // [G] all atomics done
        const int nsc = s_nslot;
        for (int i = tid; i < nsc * H1; i += 512) {
            const int v = u2.red[i];
            if (v > 0)
                atomicMax(&outi[(((size_t)(b << 10) + s_slotc[i >> 8]) << 8) + (i & 255)], v);
        }
        __syncthreads();                                // [E] red/s_* reads done; next tile may overwrite
        P0 = P0n;
    }
}

// ---------------- phase 2 fallback (recompute; used only if ws too small) ----------------
__global__ __launch_bounds__(256) void k_phase2r(
    const int* __restrict__ sorted, const float* __restrict__ pts,
    const float* __restrict__ w1, const float* __restrict__ b1,
    const float* __restrict__ g1, const float* __restrict__ be1,
    const unsigned short* __restrict__ w2T, const float* __restrict__ b2,
    const float* __restrict__ y,
    const unsigned short* __restrict__ w3T, const float* __restrict__ b3,
    const float* __restrict__ g2, const float* __restrict__ be2,
    const unsigned short* __restrict__ w4T, const float* __restrict__ b4,
    float* __restrict__ outp)
{
    __shared__ __align__(16) float s_pts[MB * CIN];
    __shared__ int   s_idx[MB], s_slot[MB], s_slotc[CAP2], s_nslot;
    __shared__ float s_w1[CIN * H0];
    __shared__ float s_b1[H0], s_g1[H0], s_be1[H0], s_b2[H0];
    __shared__ float s_b3[H1], s_g2[H1], s_be2[H1], s_b4[H1];
    __shared__ union __align__(16) {
        unsigned short a1[MB * A1S];
        struct { float2 stats[MB * 4]; float2 rowstat[MB]; } ln;
        int red[CAP2 * H1];
    } u1;
    __shared__ __align__(16) unsigned short a2[MB * A2S];

    const int tid = threadIdx.x;
    const int P0  = blockIdx.x * MB;
    const int b   = P0 >> 16;

    stage_sorted(tid, b, P0, sorted, pts, s_pts, s_idx);
    for (int i = tid; i < CIN * H0; i += 256) s_w1[i] = w1[i];
    if (tid < H0) { s_b1[tid] = b1[tid]; s_g1[tid] = g1[tid]; s_be1[tid] = be1[tid]; s_b2[tid] = b2[tid]; }
    if (tid < H1) { s_b3[tid] = b3[tid]; s_g2[tid] = g2[tid]; s_be2[tid] = be2[tid]; s_b4[tid] = b4[tid]; }
    __syncthreads();

    conv1_tile(tid, s_pts, s_w1, s_b1, s_g1, s_be1, u1.a1);
    slot_scan(tid, s_idx, s_slot, s_slotc, &s_nslot, CAP2);

    f32x4 acc2[4][2] = {};
    const int lane = tid & 63, wave = tid >> 6;
    gemm2(lane, wave, u1.a1, w2T, acc2);

    const int q = lane >> 4, colw = lane & 15;
    {
        const int n0 = wave * 32;
#pragma unroll
        for (int mt = 0; mt < 4; ++mt)
#pragma unroll
            for (int nt = 0; nt < 2; ++nt)
#pragma unroll
                for (int r = 0; r < 4; ++r) {
                    const int row = mt * 16 + q * 4 + r;
                    const int col = n0 + nt * 16 + colw;
                    a2[row * A2S + H0 + col] = f2bf(acc2[mt][nt][r] + s_b2[col]);
                }
    }
    {
        const int p = tid >> 2, sub = tid & 3;
        const float* yrow = y + ((size_t)((b << 10) + s_idx[p])) * H0;
#pragma unroll
        for (int j4 = 0; j4 < 8; ++j4) {
            const int c = sub * 32 + j4 * 4;
            float4 v = *(const float4*)&yrow[c];
            uint2 pk;
            pk.x = (unsigned)f2bf(v.x) | ((unsigned)f2bf(v.y) << 16);
            pk.y = (unsigned)f2bf(v.z) | ((unsigned)f2bf(v.w) << 16);
            *(uint2*)&a2[p * A2S + c] = pk;
        }
    }
    __syncthreads();

    f32x4 acc3[4][4] = {};
    const int n0 = wave * 64;
#pragma unroll
    for (int ks = 0; ks < 8; ++ks) {
        short8 af[4], bfr[4];
#pragma unroll
        for (int mt = 0; mt < 4; ++mt)
            af[mt] = *(const short8*)&a2[(mt * 16 + colw) * A2S + ks * 32 + q * 8];
#pragma unroll
        for (int nt = 0; nt < 4; ++nt)
            bfr[nt] = *(const short8*)&w3T[(n0 + nt * 16 + colw) * H1 + ks * 32 + q * 8];
#pragma unroll
        for (int mt = 0; mt < 4; ++mt)
#pragma unroll
            for (int nt = 0; nt < 4; ++nt)
                acc3[mt][nt] = __builtin_amdgcn_mfma_f32_16x16x32_bf16(
                    af[mt], bfr[nt], acc3[mt][nt], 0, 0, 0);
    }

#pragma unroll
    for (int mt = 0; mt < 4; ++mt)
#pragma unroll
        for (int nt = 0; nt < 4; ++nt)
#pragma unroll
            for (int r = 0; r < 4; ++r)
                acc3[mt][nt][r] += s_b3[n0 + nt * 16 + colw];

#pragma unroll
    for (int mt = 0; mt < 4; ++mt)
#pragma unroll
        for (int r = 0; r < 4; ++r) {
            float s = 0.f, s2 = 0.f;
#pragma unroll
            for (int nt = 0; nt < 4; ++nt) {
                float v = acc3[mt][nt][r];
                s += v; s2 = fmaf(v, v, s2);
            }
            s  += __shfl_xor(s, 1);  s  += __shfl_xor(s, 2);
            s  += __shfl_xor(s, 4);  s  += __shfl_xor(s, 8);
            s2 += __shfl_xor(s2, 1); s2 += __shfl_xor(s2, 2);
            s2 += __shfl_xor(s2, 4); s2 += __shfl_xor(s2, 8);
            if (colw == 0)
                u1.ln.stats[(mt * 16 + q * 4 + r) * 4 + wave] = make_float2(s, s2);
        }
    __syncthreads();
    if (tid < MB) {
        float S = 0.f, S2 = 0.f;
#pragma unroll
        for (int w = 0; w < 4; ++w) { float2 t = u1.ln.stats[tid * 4 + w]; S += t.x; S2 += t.y; }
        const float mean = S * (1.f / H1);
        const float rstd = rsqrtf(S2 * (1.f / H1) - mean * mean + 1e-5f);
        u1.ln.rowstat[tid] = make_float2(mean, rstd);
    }
    __syncthreads();

#pragma unroll
    for (int mt = 0; mt < 4; ++mt)
#pragma unroll
        for (int r = 0; r < 4; ++r) {
            const int row = mt * 16 + q * 4 + r;
            const float2 ms = u1.ln.rowstat[row];
#pragma unroll
            for (int nt = 0; nt < 4; ++nt) {
                const int col = n0 + nt * 16 + colw;
                float v = (acc3[mt][nt][r] - ms.x) * ms.y;
                v = fmaf(v, s_g2[col], s_be2[col]);
                a2[row * A2S + col] = f2bf(gelu(v));
            }
        }
    __syncthreads();

    for (int i = tid; i < CAP2 * H1; i += 256) u1.red[i] = 0;

    f32x4 acc4[4][4] = {};
#pragma unroll
    for (int ks = 0; ks < 8; ++ks) {
        short8 af[4], bfr[4];
#pragma unroll
        for (int mt = 0; mt < 4; ++mt)
            af[mt] = *(const short8*)&a2[(mt * 16 + colw) * A2S + ks * 32 + q * 8];
#pragma unroll
        for (int nt = 0; nt < 4; ++nt)
            bfr[nt] = *(const short8*)&w4T[(n0 + nt * 16 + colw) * H1 + ks * 32 + q * 8];
#pragma unroll
        for (int mt = 0; mt < 4; ++mt)
#pragma unroll
            for (int nt = 0; nt < 4; ++nt)
                acc4[mt][nt] = __builtin_amdgcn_mfma_f32_16x16x32_bf16(
                    af[mt], bfr[nt], acc4[mt][nt], 0, 0, 0);
    }
    __syncthreads();

    int* outi = (int*)outp;
#pragma unroll
    for (int mt = 0; mt < 4; ++mt)
#pragma unroll
        for (int nt = 0; nt < 4; ++nt)
#pragma unroll
            for (int r = 0; r < 4; ++r) {
                const int row = mt * 16 + q * 4 + r;
                const int col = n0 + nt * 16 + colw;
                const float v = acc4[mt][nt][r] + s_b4[col];
                if (v > 0.f) {
                    const int s = s_slot[row];
                    if (s < CAP2)
                        atomicMax(&u1.red[s * H1 + col], __float_as_int(v));
                    else
                        atomicMax(&outi[(((size_t)(b << 10) + s_idx[row]) << 8) + col],
                                  __float_as_int(v));
                }
            }
    __syncthreads();
    const int nsc = s_nslot;
    for (int i = tid; i < nsc * H1; i += 256) {
        const int v = u1.red[i];
        if (v > 0)
            atomicMax(&outi[(((size_t)(b << 10) + s_slotc[i >> 8]) << 8) + (i & 255)], v);
    }
}

extern "C" void kernel_launch(void* const* d_in, const int* in_sizes, int n_in,
                              void* d_out, int out_size, void* d_ws, size_t ws_size,
                              hipStream_t stream)
{
    const float* pts = (const float*)d_in[0];
    const int*   nn  = (const int*)d_in[1];
    // d_in[2] = center_number (1024), fixed
    const float* w1  = (const float*)d_in[3];
    const float* b1  = (const float*)d_in[4];
    const float* g1  = (const float*)d_in[5];
    const float* be1 = (const float*)d_in[6];
    const float* w2  = (const float*)d_in[7];
    const float* b2  = (const float*)d_in[8];
    const float* w3  = (const float*)d_in[9];
    const float* b3  = (const float*)d_in[10];
    const float* g2  = (const float*)d_in[11];
    const float* be2 = (const float*)d_in[12];
    const float* w4  = (const float*)d_in[13];
    const float* b4  = (const float*)d_in[14];

    if (ws_size < WS_NEED) return;   // fail loudly rather than corrupt memory

    char* ws = (char*)d_ws;
    float*          y      = (float*)(ws);
    unsigned short* w2T    = (unsigned short*)(ws + W2T_OFF);
    unsigned short* w3T    = (unsigned short*)(ws + W3T_OFF);
    unsigned short* w4T    = (unsigned short*)(ws + W4T_OFF);
    int*            sorted = (int*)(ws + SORT_OFF);
    int*            ch     = (int*)(ws + CH_OFF);
    int*            cb     = (int*)(ws + CB_OFF);
    int*            nzr    = (int*)(ws + NZR_OFF);
    unsigned short* yq     = (unsigned short*)(ws + YQ_OFF);
    unsigned short* xq     = (unsigned short*)(ws + XQ_OFF);
    float* outp = (float*)d_out;
    const bool have_xq = ws_size >= WS_XQ;

    hipMemsetAsync(y, 0, Y_BYTES, stream);
    hipMemsetAsync(outp, 0, (size_t)out_size * sizeof(float), stream);

    k_prep<<<576, 256, 0, stream>>>(w2, w3, w4, w2T, w3T, w4T);
    k_hist<<<BATCH * NCHUNK, 256, 0, stream>>>(nn, ch);
    k_scan<<<1, 256, 0, stream>>>(ch, cb, nzr);
    k_scatter<<<BATCH * NCHUNK, 256, 0, stream>>>(nn, cb, sorted);

    const int nblk = BATCH * NPTS / MB;   // 8192
    if (have_xq) {
        k_phase1<true><<<nblk, 256, 0, stream>>>(sorted, pts, nzr, w1, b1, g1, be1, w2T, b2, y, xq);
        k_yq<<<BATCH * NCTR * H0 / 4 / 256, 256, 0, stream>>>(y, yq);
        k_phase2x<<<P2GRID, 512, 0, stream>>>(sorted, xq, yq, nzr, w3T, b3, g2, be2, w4T, b4, outp);
    } else {
        k_phase1<false><<<nblk, 256, 0, stream>>>(sorted, pts, nzr, w1, b1, g1, be1, w2T, b2, y, nullptr);
        k_phase2r<<<nblk, 256, 0, stream>>>(sorted, pts, w1, b1, g1, be1, w2T, b2, y,
                                            w3T, b3, g2, be2, w4T, b4, outp);
    }
}

// Round 14
// 432.789 us; speedup vs baseline: 2.2333x; 2.2333x over previous
//
#include <hip/hip_runtime.h>

typedef short short8 __attribute__((ext_vector_type(8)));
typedef float f32x4 __attribute__((ext_vector_type(4)));

#define DEVI __device__ __forceinline__

constexpr int BATCH = 8;
constexpr int NPTS  = 65536;     // points per batch
constexpr int CIN   = 6;
constexpr int H0    = 128;
constexpr int H1    = 256;
constexpr int NCTR  = 1024;
constexpr int MB    = 64;        // points per block
constexpr int NCHUNK = 8;        // sort chunks per batch
constexpr int CHSZ  = NPTS / NCHUNK;   // 8192

// a-tile strides (shorts), padded for bank-conflict-free ds_read_b128
constexpr int A1S = 136;         // 128 + 8
constexpr int A2S = 264;         // 256 + 8

constexpr int CAP1 = 8;          // LDS-reduced slots, phase1 (8*128*4 = 4 KB)
constexpr int CAP2 = 8;          // phase2 (8*256*4 = 8 KB)

// workspace layout
constexpr size_t Y_BYTES  = (size_t)BATCH * NCTR * H0 * 4;      // 4 MiB fp32
constexpr size_t W2T_OFF  = Y_BYTES;
constexpr size_t W3T_OFF  = W2T_OFF + (size_t)H0 * H0 * 2;
constexpr size_t W4T_OFF  = W3T_OFF + (size_t)H1 * H1 * 2;
constexpr size_t SORT_OFF = W4T_OFF + (size_t)H1 * H1 * 2;
constexpr size_t CH_OFF   = SORT_OFF + (size_t)BATCH * NPTS * 4;
constexpr size_t CB_OFF   = CH_OFF + (size_t)BATCH * NCHUNK * NCTR * 4;
constexpr size_t NZR_OFF  = CB_OFF + (size_t)BATCH * NCHUNK * NCTR * 4;
constexpr size_t YQ_OFF   = NZR_OFF + (size_t)BATCH * NCTR * 4;
constexpr size_t WS_NEED  = YQ_OFF + (size_t)BATCH * NCTR * H0 * 2;       // ~9 MB
constexpr size_t XQ_OFF   = WS_NEED;
constexpr size_t WS_XQ    = XQ_OFF + (size_t)BATCH * NPTS * H0 * 2;       // +128 MB

DEVI unsigned short f2bf(float f) {
    unsigned u = __float_as_uint(f);
    u += 0x7fffu + ((u >> 16) & 1u);          // round-to-nearest-even
    return (unsigned short)(u >> 16);
}
// tanh-form GELU, branch-free (~8 VALU vs ~70 for erff). |err| <~1e-3, fine at bf16 scale.
DEVI float gelu(float x) {
    const float x3 = x * x * x;
    const float u = fmaf(x3, -0.07135481283f, -1.5957691216f * x);
    return x * __builtin_amdgcn_rcpf(1.f + __expf(u));
}

// ---------------- conv1: gelu(LN(p@w1+b1)) -> a1[64][A1S] bf16 ----------------
DEVI void conv1_tile(int tid, const float* s_pts, const float* s_w1,
                     const float* s_b1, const float* s_g1, const float* s_be1,
                     unsigned short* a1)
{
    const int p = tid >> 2, sub = tid & 3;    // 4 threads per point, c = 4j+sub
    float pt[CIN];
#pragma unroll
    for (int k = 0; k < CIN; ++k) pt[k] = s_pts[p * CIN + k];
    float h[32];
#pragma unroll
    for (int j = 0; j < 32; ++j) {
        const int c = (j << 2) + sub;
        float a = s_b1[c];
#pragma unroll
        for (int k = 0; k < CIN; ++k) a = fmaf(pt[k], s_w1[k * H0 + c], a);
        h[j] = a;
    }
    float s = 0.f, s2 = 0.f;
#pragma unroll
    for (int j = 0; j < 32; ++j) { s += h[j]; s2 = fmaf(h[j], h[j], s2); }
    s  += __shfl_xor(s, 1);  s  += __shfl_xor(s, 2);
    s2 += __shfl_xor(s2, 1); s2 += __shfl_xor(s2, 2);
    const float mean = s * (1.f / H0);
    const float rstd = rsqrtf(s2 * (1.f / H0) - mean * mean + 1e-5f);
#pragma unroll
    for (int j = 0; j < 32; ++j) {
        const int c = (j << 2) + sub;
        float v = fmaf((h[j] - mean) * rstd, s_g1[c], s_be1[c]);
        a1[p * A1S + c] = f2bf(gelu(v));
    }
}

// ---------------- GEMM2 (shared helper) ----------------
DEVI void gemm2(int lane, int wave, const unsigned short* a1,
                const unsigned short* __restrict__ w2T, f32x4 (&acc)[4][2])
{
    const int q = lane >> 4, colw = lane & 15, n0 = wave * 32;
#pragma unroll
    for (int ks = 0; ks < 4; ++ks) {
        short8 af[4], bfr[2];
#pragma unroll
        for (int mt = 0; mt < 4; ++mt)
            af[mt] = *(const short8*)&a1[(mt * 16 + colw) * A1S + ks * 32 + q * 8];
#pragma unroll
        for (int nt = 0; nt < 2; ++nt)
            bfr[nt] = *(const short8*)&w2T[(n0 + nt * 16 + colw) * H0 + ks * 32 + q * 8];
#pragma unroll
        for (int mt = 0; mt < 4; ++mt)
#pragma unroll
            for (int nt = 0; nt < 2; ++nt)
                acc[mt][nt] = __builtin_amdgcn_mfma_f32_16x16x32_bf16(
                    af[mt], bfr[nt], acc[mt][nt], 0, 0, 0);
    }
}

// stage sorted point metadata (tid<64). Clamped: no OOB even on garbage input.
DEVI void stage_sorted(int tid, int b, int P0, const int* __restrict__ sorted,
                       const float* __restrict__ pts, float* s_pts, int* s_idx)
{
    if (tid < 64) {
        const int val = sorted[P0 + tid];
        const int pid = val & 0xFFFF;
        s_idx[tid] = (val >> 16) & (NCTR - 1);
        const float* prow = &pts[((size_t)(b << 16) + pid) * CIN];
#pragma unroll
        for (int k = 0; k < CIN; ++k) s_pts[tid * CIN + k] = prow[k];
    }
}

// parallel slot assignment (fallback path only): Hillis-Steele scan.
DEVI void slot_scan(int tid, const int* s_idx, int* s_slot, int* s_slotc, int* s_nslot, int cap)
{
    int f = 0;
    if (tid < MB) {
        f = (tid > 0 && s_idx[tid] != s_idx[tid - 1]) ? 1 : 0;
        s_slot[tid] = f;
    }
    __syncthreads();
#pragma unroll
    for (int off = 1; off < MB; off <<= 1) {
        int t = 0;
        if (tid < MB && tid >= off) t = s_slot[tid - off];
        __syncthreads();
        if (tid < MB) s_slot[tid] += t;
        __syncthreads();
    }
    if (tid < MB) {
        const int s = s_slot[tid];
        if ((f || tid == 0) && s < cap) s_slotc[s] = s_idx[tid];
        if (tid == MB - 1) *s_nslot = (s + 1 < cap) ? (s + 1) : cap;
    }
    __syncthreads();
}

// ---------------- prep: weight convert/transpose ----------------
__global__ __launch_bounds__(256) void k_prep(
    const float* __restrict__ w2, const float* __restrict__ w3,
    const float* __restrict__ w4,
    unsigned short* __restrict__ w2T, unsigned short* __restrict__ w3T,
    unsigned short* __restrict__ w4T)
{
    int t = blockIdx.x * 256 + threadIdx.x;
    if (t < H0 * H0) {
        int n = t >> 7, k = t & 127;
        w2T[t] = f2bf(w2[k * H0 + n]);
    }
    int t3 = t - H0 * H0;
    if (t3 >= 0 && t3 < H1 * H1) {
        int n = t3 >> 8, k = t3 & 255;
        w3T[t3] = f2bf(w3[k * H1 + n]);
    }
    int t4 = t - (H0 * H0 + H1 * H1);
    if (t4 >= 0 && t4 < H1 * H1) {
        int n = t4 >> 8, k = t4 & 255;
        w4T[t4] = f2bf(w4[k * H1 + n]);
    }
}

// ---------------- y (fp32) -> yq (bf16) ----------------
__global__ __launch_bounds__(256) void k_yq(const float* __restrict__ y,
                                            unsigned short* __restrict__ yq)
{
    const int i = blockIdx.x * 256 + threadIdx.x;   // 1 elem4 per thread
    const float4 v = *(const float4*)&y[(size_t)i * 4];
    uint2 pk;
    pk.x = (unsigned)f2bf(v.x) | ((unsigned)f2bf(v.y) << 16);
    pk.y = (unsigned)f2bf(v.z) | ((unsigned)f2bf(v.w) << 16);
    *(uint2*)&yq[(size_t)i * 4] = pk;
}

// ---------------- sort: chunked hist -> deterministic 2-level scan -> scatter ----
__global__ __launch_bounds__(256) void k_hist(const int* __restrict__ nn,
                                              int* __restrict__ ch)
{
    __shared__ int lh[NCTR];
    const int tid = threadIdx.x;
    const int b = blockIdx.x >> 3, k = blockIdx.x & 7;
    const int base = (b << 16) + k * CHSZ;
    for (int c = tid; c < NCTR; c += 256) lh[c] = 0;
    __syncthreads();
    for (int i = tid; i < CHSZ; i += 256)
        atomicAdd(&lh[nn[base + i] & (NCTR - 1)], 1);
    __syncthreads();
    for (int c = tid; c < NCTR; c += 256) ch[(blockIdx.x << 10) + c] = lh[c];
}

// scan: per-chunk cursor bases + nzrank (# nonempty centers < c) per batch
__global__ __launch_bounds__(256) void k_scan(const int* __restrict__ ch,
                                              int* __restrict__ cb,
                                              int* __restrict__ nzr)
{
    __shared__ int part[256], partz[256];
    const int tid = threadIdx.x;
    const int b = tid >> 5, t = tid & 31;     // 32 threads per batch, 32 centers each
    const int c0 = t * 32;
    int tot = 0, totz = 0;
    for (int c = c0; c < c0 + 32; ++c) {
        int cnt = 0;
        for (int k = 0; k < NCHUNK; ++k)
            cnt += ch[((b * NCHUNK + k) << 10) + c];
        tot += cnt; totz += (cnt > 0);
    }
    part[tid] = tot; partz[tid] = totz;
    __syncthreads();
    if (t == 0) {                              // serial scan of 32 partials per batch
        int run = 0, runz = 0;
        for (int i = 0; i < 32; ++i) {
            const int v  = part[(b << 5) + i];  part[(b << 5) + i]  = run;  run  += v;
            const int vz = partz[(b << 5) + i]; partz[(b << 5) + i] = runz; runz += vz;
        }
    }
    __syncthreads();
    int run = part[tid], runz = partz[tid];
    for (int c = c0; c < c0 + 32; ++c) {
        int cnt = 0;
        for (int k = 0; k < NCHUNK; ++k) {
            const int idx = ((b * NCHUNK + k) << 10) + c;
            cb[idx] = run; run += ch[idx]; cnt += ch[idx];
        }
        nzr[(b << 10) + c] = runz;
        runz += (cnt > 0);
    }
}

__global__ __launch_bounds__(256) void k_scatter(const int* __restrict__ nn,
                                                 const int* __restrict__ cb,
                                                 int* __restrict__ sorted)
{
    __shared__ int cur[NCTR];
    const int tid = threadIdx.x;
    const int b = blockIdx.x >> 3, k = blockIdx.x & 7;
    const int base = (b << 16) + k * CHSZ;
    for (int c = tid; c < NCTR; c += 256) cur[c] = cb[(blockIdx.x << 10) + c];
    __syncthreads();
    for (int i = tid; i < CHSZ; i += 256) {
        const int c = nn[base + i] & (NCTR - 1);
        const int pos = atomicAdd(&cur[c], 1);
        if ((unsigned)pos < (unsigned)NPTS)             // paranoia: cannot fault
            sorted[(b << 16) + pos] = (k * CHSZ + i) | (c << 16);
    }
}

// ---------------- phase 1: conv1 MLP + slot-reduced max into y (+ optional x store) ----
template <bool XQ>
__global__ __launch_bounds__(256, 4) void k_phase1(
    const int* __restrict__ sorted, const float* __restrict__ pts,
    const int* __restrict__ nzr,
    const float* __restrict__ w1, const float* __restrict__ b1,
    const float* __restrict__ g1, const float* __restrict__ be1,
    const unsigned short* __restrict__ w2T, const float* __restrict__ b2,
    float* __restrict__ y, unsigned short* __restrict__ xq)
{
    __shared__ __align__(16) float s_pts[MB * CIN];
    __shared__ int   s_idx[MB], s_slot[MB], s_slotc[CAP1], s_nslot;
    __shared__ float s_w1[CIN * H0];
    __shared__ float s_b1[H0], s_g1[H0], s_be1[H0];
    __shared__ __align__(16) unsigned short a1[MB * A1S];
    __shared__ int   red1[CAP1 * H0];

    const int tid = threadIdx.x;
    const int P0  = blockIdx.x * MB;
    const int b   = P0 >> 16;
    const int lane = tid & 63, wave = tid >> 6;
    const int q = lane >> 4, colw = lane & 15, n0 = wave * 32;

    if (tid < 64) {
        const int val = sorted[P0 + tid];
        const int pid = val & 0xFFFF;
        const int c   = (val >> 16) & (NCTR - 1);
        const int c0v = (sorted[P0] >> 16) & (NCTR - 1);
        s_idx[tid] = c;
        const int sl = nzr[(b << 10) + c] - nzr[(b << 10) + c0v];  // run rank in tile
        s_slot[tid] = sl;
        if (tid == 63) s_nslot = (sl + 1 < CAP1) ? (sl + 1) : CAP1;
        const float* prow = &pts[((size_t)(b << 16) + pid) * CIN];
#pragma unroll
        for (int k = 0; k < CIN; ++k) s_pts[tid * CIN + k] = prow[k];
    }
    for (int i = tid; i < CIN * H0; i += 256) s_w1[i] = w1[i];
    if (tid < H0) { s_b1[tid] = b1[tid]; s_g1[tid] = g1[tid]; s_be1[tid] = be1[tid]; }
    for (int i = tid; i < CAP1 * H0; i += 256) red1[i] = 0;
    __syncthreads();                                    // [A]

    if (tid < 64) {
        const int sl = s_slot[tid];
        if (sl < CAP1 && (tid == 0 || s_idx[tid] != s_idx[tid - 1]))
            s_slotc[sl] = s_idx[tid];
    }
    conv1_tile(tid, s_pts, s_w1, s_b1, s_g1, s_be1, a1);
    __syncthreads();                                    // [B] a1 + slotc ready

    f32x4 acc[4][2] = {};
    gemm2(lane, wave, a1, w2T, acc);
    if (XQ) __syncthreads();              // [C] a1 MFMA reads done before x restage

    // per-thread bias cols (2) straight from global (L2-hot), loaded at use
    float b2reg[2];
#pragma unroll
    for (int nt = 0; nt < 2; ++nt) b2reg[nt] = b2[n0 + nt * 16 + colw];

    int* yi = (int*)y;
    // ---- slot-grouped in-register max, then few atomics ----
    {
        float vm[2] = {-3.4e38f, -3.4e38f};
        int cur = s_slot[q * 4], curc = s_idx[q * 4];
#pragma unroll
        for (int mt = 0; mt < 4; ++mt)
#pragma unroll
            for (int r = 0; r < 4; ++r) {
                const int row = mt * 16 + q * 4 + r;
                const int s = s_slot[row];
                if (s != cur) {
#pragma unroll
                    for (int nt = 0; nt < 2; ++nt) {
                        if (vm[nt] > 0.f) {
                            const int col = n0 + nt * 16 + colw;
                            if (cur < CAP1) atomicMax(&red1[cur * H0 + col], __float_as_int(vm[nt]));
                            else atomicMax(&yi[(((b << 10) + curc) << 7) + col], __float_as_int(vm[nt]));
                        }
                        vm[nt] = -3.4e38f;
                    }
                    cur = s; curc = s_idx[row];
                }
#pragma unroll
                for (int nt = 0; nt < 2; ++nt) {
                    const float v = acc[mt][nt][r] + b2reg[nt];
                    if (XQ) a1[row * A1S + n0 + nt * 16 + colw] = f2bf(v);
                    vm[nt] = fmaxf(vm[nt], v);
                }
            }
#pragma unroll
        for (int nt = 0; nt < 2; ++nt)
            if (vm[nt] > 0.f) {
                const int col = n0 + nt * 16 + colw;
                if (cur < CAP1) atomicMax(&red1[cur * H0 + col], __float_as_int(vm[nt]));
                else atomicMax(&yi[(((b << 10) + curc) << 7) + col], __float_as_int(vm[nt]));
            }
    }
    __syncthreads();                                    // [D]
    const int nsc = s_nslot;
    for (int i = tid; i < nsc * H0; i += 256) {
        const int v = red1[i];
        if (v > 0)
            atomicMax(&yi[(((b << 10) + s_slotc[i >> 7]) << 7) + (i & 127)], v);
    }
    if (XQ) {   // coalesced x store: 1024 short8 units
        for (int i = tid; i < MB * (H0 / 8); i += 256) {
            const int row = i >> 4, u = (i & 15) * 8;
            *(short8*)&xq[((size_t)P0 + row) * H0 + u] = *(const short8*)&a1[row * A1S + u];
        }
    }
}

// ---------------- phase 2 (XQ): load x, gather yq, conv2 MLP + slot-reduced max ----
__global__ __launch_bounds__(256, 4) void k_phase2x(
    const int* __restrict__ sorted, const unsigned short* __restrict__ xq,
    const unsigned short* __restrict__ yq, const int* __restrict__ nzr,
    const unsigned short* __restrict__ w3T, const float* __restrict__ b3,
    const float* __restrict__ g2, const float* __restrict__ be2,
    const unsigned short* __restrict__ w4T, const float* __restrict__ b4,
    float* __restrict__ outp)
{
    __shared__ int   s_idx[MB], s_slot[MB], s_slotc[CAP2], s_nslot;
    __shared__ __align__(16) unsigned short a2[MB * A2S];   // union'd with red
    __shared__ float2 s_stats[MB * 4];
    __shared__ float2 s_rowstat[MB];

    const int tid = threadIdx.x;
    const int P0  = blockIdx.x * MB;
    const int b   = P0 >> 16;
    const int lane = tid & 63, wave = tid >> 6;
    const int q = lane >> 4, colw = lane & 15;
    const int n0 = wave * 64;

    // ---- staging: direct load->LDS (transient regs only; TLP hides latency) ----
    const int rowp = tid >> 2, sub = tid & 3;
    {
        const int sval = sorted[P0 + rowp];              // broadcast x4 (L2-hot)
        const int cp = (sval >> 16) & (NCTR - 1);
        const unsigned short* xsrc = &xq[((size_t)P0 + rowp) * H0 + sub * 32];
        unsigned short*       dx   = &a2[rowp * A2S + H0 + sub * 32];
        const unsigned short* ysrc = &yq[((size_t)((b << 10) + cp)) * H0 + sub * 32];
        unsigned short*       dy   = &a2[rowp * A2S + sub * 32];
#pragma unroll
        for (int u = 0; u < 4; ++u) {
            *(short8*)(dx + u * 8) = *(const short8*)(xsrc + u * 8);
            *(short8*)(dy + u * 8) = *(const short8*)(ysrc + u * 8);
        }
    }
    if (tid < 64) {
        const int c   = (sorted[P0 + tid] >> 16) & (NCTR - 1);
        const int c0v = (sorted[P0] >> 16) & (NCTR - 1);
        s_idx[tid] = c;
        const int sl = nzr[(b << 10) + c] - nzr[(b << 10) + c0v];
        s_slot[tid] = sl;
        if (tid == 63) s_nslot = (sl + 1 < CAP2) ? (sl + 1) : CAP2;
    }
    __syncthreads();                                    // [A] a2 + slots ready

    if (tid < 64) {
        const int sl = s_slot[tid];
        if (sl < CAP2 && (tid == 0 || s_idx[tid] != s_idx[tid - 1]))
            s_slotc[sl] = s_idx[tid];
    }

    // ---- GEMM3: a2[64][256] @ w3T ----
    f32x4 acc3[4][4] = {};
#pragma unroll
    for (int ks = 0; ks < 8; ++ks) {
        short8 af[4], bfr[4];
#pragma unroll
        for (int mt = 0; mt < 4; ++mt)
            af[mt] = *(const short8*)&a2[(mt * 16 + colw) * A2S + ks * 32 + q * 8];
#pragma unroll
        for (int nt = 0; nt < 4; ++nt)
            bfr[nt] = *(const short8*)&w3T[(n0 + nt * 16 + colw) * H1 + ks * 32 + q * 8];
#pragma unroll
        for (int mt = 0; mt < 4; ++mt)
#pragma unroll
            for (int nt = 0; nt < 4; ++nt)
                acc3[mt][nt] = __builtin_amdgcn_mfma_f32_16x16x32_bf16(
                    af[mt], bfr[nt], acc3[mt][nt], 0, 0, 0);
    }

    // + b3 (loaded at use, L2-hot), then LN stats (sum / sumsq per row of 256)
    {
        float b3r[4];
#pragma unroll
        for (int nt = 0; nt < 4; ++nt) b3r[nt] = b3[n0 + nt * 16 + colw];
#pragma unroll
        for (int mt = 0; mt < 4; ++mt)
#pragma unroll
            for (int nt = 0; nt < 4; ++nt)
#pragma unroll
                for (int r = 0; r < 4; ++r)
                    acc3[mt][nt][r] += b3r[nt];
    }

#pragma unroll
    for (int mt = 0; mt < 4; ++mt)
#pragma unroll
        for (int r = 0; r < 4; ++r) {
            float s = 0.f, s2 = 0.f;
#pragma unroll
            for (int nt = 0; nt < 4; ++nt) {
                float v = acc3[mt][nt][r];
                s += v; s2 = fmaf(v, v, s2);
            }
            s  += __shfl_xor(s, 1);  s  += __shfl_xor(s, 2);
            s  += __shfl_xor(s, 4);  s  += __shfl_xor(s, 8);
            s2 += __shfl_xor(s2, 1); s2 += __shfl_xor(s2, 2);
            s2 += __shfl_xor(s2, 4); s2 += __shfl_xor(s2, 8);
            if (colw == 0)
                s_stats[(mt * 16 + q * 4 + r) * 4 + wave] = make_float2(s, s2);
        }
    __syncthreads();                                    // [B]
    if (tid < MB) {
        float S = 0.f, S2 = 0.f;
#pragma unroll
        for (int w = 0; w < 4; ++w) { float2 t = s_stats[tid * 4 + w]; S += t.x; S2 += t.y; }
        const float mean = S * (1.f / H1);
        const float rstd = rsqrtf(S2 * (1.f / H1) - mean * mean + 1e-5f);
        s_rowstat[tid] = make_float2(mean, rstd);
    }
    __syncthreads();                                    // [C]

    // normalize + gelu -> h back into a2 (full 256 cols); g2/be2 loaded at use
    {
        float g2r[4], be2r[4];
#pragma unroll
        for (int nt = 0; nt < 4; ++nt) {
            const int col = n0 + nt * 16 + colw;
            g2r[nt] = g2[col]; be2r[nt] = be2[col];
        }
#pragma unroll
        for (int mt = 0; mt < 4; ++mt)
#pragma unroll
            for (int r = 0; r < 4; ++r) {
                const int row = mt * 16 + q * 4 + r;
                const float2 ms = s_rowstat[row];
#pragma unroll
                for (int nt = 0; nt < 4; ++nt) {
                    float v = (acc3[mt][nt][r] - ms.x) * ms.y;
                    v = fmaf(v, g2r[nt], be2r[nt]);
                    a2[row * A2S + n0 + nt * 16 + colw] = f2bf(gelu(v));
                }
            }
    }
    __syncthreads();                                    // [D]

    // ---- GEMM4: h[64][256] @ w4T ----
    f32x4 acc4[4][4] = {};
#pragma unroll
    for (int ks = 0; ks < 8; ++ks) {
        short8 af[4], bfr[4];
#pragma unroll
        for (int mt = 0; mt < 4; ++mt)
            af[mt] = *(const short8*)&a2[(mt * 16 + colw) * A2S + ks * 32 + q * 8];
#pragma unroll
        for (int nt = 0; nt < 4; ++nt)
            bfr[nt] = *(const short8*)&w4T[(n0 + nt * 16 + colw) * H1 + ks * 32 + q * 8];
#pragma unroll
        for (int mt = 0; mt < 4; ++mt)
#pragma unroll
            for (int nt = 0; nt < 4; ++nt)
                acc4[mt][nt] = __builtin_amdgcn_mfma_f32_16x16x32_bf16(
                    af[mt], bfr[nt], acc4[mt][nt], 0, 0, 0);
    }
    __syncthreads();                                    // [E] a2 reads done

    int* red = (int*)a2;
    for (int i = tid; i < CAP2 * H1; i += 256) red[i] = 0;
    __syncthreads();                                    // [F]

    // per-thread b4 cols loaded at use
    float b4r[4];
#pragma unroll
    for (int nt = 0; nt < 4; ++nt) b4r[nt] = b4[n0 + nt * 16 + colw];

    int* outi = (int*)outp;
    // ---- slot-grouped in-register max, then few atomics ----
    {
        float vm[4] = {-3.4e38f, -3.4e38f, -3.4e38f, -3.4e38f};
        int cur = s_slot[q * 4], curc = s_idx[q * 4];
#pragma unroll
        for (int mt = 0; mt < 4; ++mt)
#pragma unroll
            for (int r = 0; r < 4; ++r) {
                const int row = mt * 16 + q * 4 + r;
                const int s = s_slot[row];
                if (s != cur) {
#pragma unroll
                    for (int nt = 0; nt < 4; ++nt) {
                        if (vm[nt] > 0.f) {
                            const int col = n0 + nt * 16 + colw;
                            if (cur < CAP2) atomicMax(&red[cur * H1 + col], __float_as_int(vm[nt]));
                            else atomicMax(&outi[(((size_t)(b << 10) + curc) << 8) + col], __float_as_int(vm[nt]));
                        }
                        vm[nt] = -3.4e38f;
                    }
                    cur = s; curc = s_idx[row];
                }
#pragma unroll
                for (int nt = 0; nt < 4; ++nt)
                    vm[nt] = fmaxf(vm[nt], acc4[mt][nt][r] + b4r[nt]);
            }
#pragma unroll
        for (int nt = 0; nt < 4; ++nt)
            if (vm[nt] > 0.f) {
                const int col = n0 + nt * 16 + colw;
                if (cur < CAP2) atomicMax(&red[cur * H1 + col], __float_as_int(vm[nt]));
                else atomicMax(&outi[(((size_t)(b << 10) + curc) << 8) + col], __float_as_int(vm[nt]));
            }
    }
    __syncthreads();                                    // [G]
    const int nsc = s_nslot;
    for (int i = tid; i < nsc * H1; i += 256) {
        const int v = red[i];
        if (v > 0)
            atomicMax(&outi[(((size_t)(b << 10) + s_slotc[i >> 8]) << 8) + (i & 255)], v);
    }
}

// ---------------- phase 2 fallback (recompute; used only if ws too small) ----------------
__global__ __launch_bounds__(256) void k_phase2r(
    const int* __restrict__ sorted, const float* __restrict__ pts,
    const float* __restrict__ w1, const float* __restrict__ b1,
    const float* __restrict__ g1, const float* __restrict__ be1,
    const unsigned short* __restrict__ w2T, const float* __restrict__ b2,
    const float* __restrict__ y,
    const unsigned short* __restrict__ w3T, const float* __restrict__ b3,
    const float* __restrict__ g2, const float* __restrict__ be2,
    const unsigned short* __restrict__ w4T, const float* __restrict__ b4,
    float* __restrict__ outp)
{
    __shared__ __align__(16) float s_pts[MB * CIN];
    __shared__ int   s_idx[MB], s_slot[MB], s_slotc[CAP2], s_nslot;
    __shared__ float s_w1[CIN * H0];
    __shared__ float s_b1[H0], s_g1[H0], s_be1[H0], s_b2[H0];
    __shared__ float s_b3[H1], s_g2[H1], s_be2[H1], s_b4[H1];
    __shared__ union __align__(16) {
        unsigned short a1[MB * A1S];
        struct { float2 stats[MB * 4]; float2 rowstat[MB]; } ln;
        int red[CAP2 * H1];
    } u1;
    __shared__ __align__(16) unsigned short a2[MB * A2S];

    const int tid = threadIdx.x;
    const int P0  = blockIdx.x * MB;
    const int b   = P0 >> 16;

    stage_sorted(tid, b, P0, sorted, pts, s_pts, s_idx);
    for (int i = tid; i < CIN * H0; i += 256) s_w1[i] = w1[i];
    if (tid < H0) { s_b1[tid] = b1[tid]; s_g1[tid] = g1[tid]; s_be1[tid] = be1[tid]; s_b2[tid] = b2[tid]; }
    if (tid < H1) { s_b3[tid] = b3[tid]; s_g2[tid] = g2[tid]; s_be2[tid] = be2[tid]; s_b4[tid] = b4[tid]; }
    __syncthreads();

    conv1_tile(tid, s_pts, s_w1, s_b1, s_g1, s_be1, u1.a1);
    slot_scan(tid, s_idx, s_slot, s_slotc, &s_nslot, CAP2);

    f32x4 acc2[4][2] = {};
    const int lane = tid & 63, wave = tid >> 6;
    gemm2(lane, wave, u1.a1, w2T, acc2);

    const int q = lane >> 4, colw = lane & 15;
    {
        const int n0 = wave * 32;
#pragma unroll
        for (int mt = 0; mt < 4; ++mt)
#pragma unroll
            for (int nt = 0; nt < 2; ++nt)
#pragma unroll
                for (int r = 0; r < 4; ++r) {
                    const int row = mt * 16 + q * 4 + r;
                    const int col = n0 + nt * 16 + colw;
                    a2[row * A2S + H0 + col] = f2bf(acc2[mt][nt][r] + s_b2[col]);
                }
    }
    {
        const int p = tid >> 2, sub = tid & 3;
        const float* yrow = y + ((size_t)((b << 10) + s_idx[p])) * H0;
#pragma unroll
        for (int j4 = 0; j4 < 8; ++j4) {
            const int c = sub * 32 + j4 * 4;
            float4 v = *(const float4*)&yrow[c];
            uint2 pk;
            pk.x = (unsigned)f2bf(v.x) | ((unsigned)f2bf(v.y) << 16);
            pk.y = (unsigned)f2bf(v.z) | ((unsigned)f2bf(v.w) << 16);
            *(uint2*)&a2[p * A2S + c] = pk;
        }
    }
    __syncthreads();

    f32x4 acc3[4][4] = {};
    const int n0 = wave * 64;
#pragma unroll
    for (int ks = 0; ks < 8; ++ks) {
        short8 af[4], bfr[4];
#pragma unroll
        for (int mt = 0; mt < 4; ++mt)
            af[mt] = *(const short8*)&a2[(mt * 16 + colw) * A2S + ks * 32 + q * 8];
#pragma unroll
        for (int nt = 0; nt < 4; ++nt)
            bfr[nt] = *(const short8*)&w3T[(n0 + nt * 16 + colw) * H1 + ks * 32 + q * 8];
#pragma unroll
        for (int mt = 0; mt < 4; ++mt)
#pragma unroll
            for (int nt = 0; nt < 4; ++nt)
                acc3[mt][nt] = __builtin_amdgcn_mfma_f32_16x16x32_bf16(
                    af[mt], bfr[nt], acc3[mt][nt], 0, 0, 0);
    }

#pragma unroll
    for (int mt = 0; mt < 4; ++mt)
#pragma unroll
        for (int nt = 0; nt < 4; ++nt)
#pragma unroll
            for (int r = 0; r < 4; ++r)
                acc3[mt][nt][r] += s_b3[n0 + nt * 16 + colw];

#pragma unroll
    for (int mt = 0; mt < 4; ++mt)
#pragma unroll
        for (int r = 0; r < 4; ++r) {
            float s = 0.f, s2 = 0.f;
#pragma unroll
            for (int nt = 0; nt < 4; ++nt) {
                float v = acc3[mt][nt][r];
                s += v; s2 = fmaf(v, v, s2);
            }
            s  += __shfl_xor(s, 1);  s  += __shfl_xor(s, 2);
            s  += __shfl_xor(s, 4);  s  += __shfl_xor(s, 8);
            s2 += __shfl_xor(s2, 1); s2 += __shfl_xor(s2, 2);
            s2 += __shfl_xor(s2, 4); s2 += __shfl_xor(s2, 8);
            if (colw == 0)
                u1.ln.stats[(mt * 16 + q * 4 + r) * 4 + wave] = make_float2(s, s2);
        }
    __syncthreads();
    if (tid < MB) {
        float S = 0.f, S2 = 0.f;
#pragma unroll
        for (int w = 0; w < 4; ++w) { float2 t = u1.ln.stats[tid * 4 + w]; S += t.x; S2 += t.y; }
        const float mean = S * (1.f / H1);
        const float rstd = rsqrtf(S2 * (1.f / H1) - mean * mean + 1e-5f);
        u1.ln.rowstat[tid] = make_float2(mean, rstd);
    }
    __syncthreads();

#pragma unroll
    for (int mt = 0; mt < 4; ++mt)
#pragma unroll
        for (int r = 0; r < 4; ++r) {
            const int row = mt * 16 + q * 4 + r;
            const float2 ms = u1.ln.rowstat[row];
#pragma unroll
            for (int nt = 0; nt < 4; ++nt) {
                const int col = n0 + nt * 16 + colw;
                float v = (acc3[mt][nt][r] - ms.x) * ms.y;
                v = fmaf(v, s_g2[col], s_be2[col]);
                a2[row * A2S + col] = f2bf(gelu(v));
            }
        }
    __syncthreads();

    for (int i = tid; i < CAP2 * H1; i += 256) u1.red[i] = 0;

    f32x4 acc4[4][4] = {};
#pragma unroll
    for (int ks = 0; ks < 8; ++ks) {
        short8 af[4], bfr[4];
#pragma unroll
        for (int mt = 0; mt < 4; ++mt)
            af[mt] = *(const short8*)&a2[(mt * 16 + colw) * A2S + ks * 32 + q * 8];
#pragma unroll
        for (int nt = 0; nt < 4; ++nt)
            bfr[nt] = *(const short8*)&w4T[(n0 + nt * 16 + colw) * H1 + ks * 32 + q * 8];
#pragma unroll
        for (int mt = 0; mt < 4; ++mt)
#pragma unroll
            for (int nt = 0; nt < 4; ++nt)
                acc4[mt][nt] = __builtin_amdgcn_mfma_f32_16x16x32_bf16(
                    af[mt], bfr[nt], acc4[mt][nt], 0, 0, 0);
    }
    __syncthreads();

    int* outi = (int*)outp;
#pragma unroll
    for (int mt = 0; mt < 4; ++mt)
#pragma unroll
        for (int nt = 0; nt < 4; ++nt)
#pragma unroll
            for (int r = 0; r < 4; ++r) {
                const int row = mt * 16 + q * 4 + r;
                const int col = n0 + nt * 16 + colw;
                const float v = acc4[mt][nt][r] + s_b4[col];
                if (v > 0.f) {
                    const int s = s_slot[row];
                    if (s < CAP2)
                        atomicMax(&u1.red[s * H1 + col], __float_as_int(v));
                    else
                        atomicMax(&outi[(((size_t)(b << 10) + s_idx[row]) << 8) + col],
                                  __float_as_int(v));
                }
            }
    __syncthreads();
    const int nsc = s_nslot;
    for (int i = tid; i < nsc * H1; i += 256) {
        const int v = u1.red[i];
        if (v > 0)
            atomicMax(&outi[(((size_t)(b << 10) + s_slotc[i >> 8]) << 8) + (i & 255)], v);
    }
}

extern "C" void kernel_launch(void* const* d_in, const int* in_sizes, int n_in,
                              void* d_out, int out_size, void* d_ws, size_t ws_size,
                              hipStream_t stream)
{
    const float* pts = (const float*)d_in[0];
    const int*   nn  = (const int*)d_in[1];
    // d_in[2] = center_number (1024), fixed
    const float* w1  = (const float*)d_in[3];
    const float* b1  = (const float*)d_in[4];
    const float* g1  = (const float*)d_in[5];
    const float* be1 = (const float*)d_in[6];
    const float* w2  = (const float*)d_in[7];
    const float* b2  = (const float*)d_in[8];
    const float* w3  = (const float*)d_in[9];
    const float* b3  = (const float*)d_in[10];
    const float* g2  = (const float*)d_in[11];
    const float* be2 = (const float*)d_in[12];
    const float* w4  = (const float*)d_in[13];
    const float* b4  = (const float*)d_in[14];

    if (ws_size < WS_NEED) return;   // fail loudly rather than corrupt memory

    char* ws = (char*)d_ws;
    float*          y      = (float*)(ws);
    unsigned short* w2T    = (unsigned short*)(ws + W2T_OFF);
    unsigned short* w3T    = (unsigned short*)(ws + W3T_OFF);
    unsigned short* w4T    = (unsigned short*)(ws + W4T_OFF);
    int*            sorted = (int*)(ws + SORT_OFF);
    int*            ch     = (int*)(ws + CH_OFF);
    int*            cb     = (int*)(ws + CB_OFF);
    int*            nzr    = (int*)(ws + NZR_OFF);
    unsigned short* yq     = (unsigned short*)(ws + YQ_OFF);
    unsigned short* xq     = (unsigned short*)(ws + XQ_OFF);
    float* outp = (float*)d_out;
    const bool have_xq = ws_size >= WS_XQ;

    hipMemsetAsync(y, 0, Y_BYTES, stream);
    hipMemsetAsync(outp, 0, (size_t)out_size * sizeof(float), stream);

    k_prep<<<576, 256, 0, stream>>>(w2, w3, w4, w2T, w3T, w4T);
    k_hist<<<BATCH * NCHUNK, 256, 0, stream>>>(nn, ch);
    k_scan<<<1, 256, 0, stream>>>(ch, cb, nzr);
    k_scatter<<<BATCH * NCHUNK, 256, 0, stream>>>(nn, cb, sorted);

    const int nblk = BATCH * NPTS / MB;   // 8192
    if (have_xq) {
        k_phase1<true><<<nblk, 256, 0, stream>>>(sorted, pts, nzr, w1, b1, g1, be1, w2T, b2, y, xq);
        k_yq<<<BATCH * NCTR * H0 / 4 / 256, 256, 0, stream>>>(y, yq);
        k_phase2x<<<nblk, 256, 0, stream>>>(sorted, xq, yq, nzr, w3T, b3, g2, be2, w4T, b4, outp);
    } else {
        k_phase1<false><<<nblk, 256, 0, stream>>>(sorted, pts, nzr, w1, b1, g1, be1, w2T, b2, y, nullptr);
        k_phase2r<<<nblk, 256, 0, stream>>>(sorted, pts, w1, b1, g1, be1, w2T, b2, y,
                                            w3T, b3, g2, be2, w4T, b4, outp);
    }
}